// Round 8
// baseline (149.183 us; speedup 1.0000x reference)
//
#include <hip/hip_runtime.h>
#include <hip/hip_bf16.h>

#define NP 512                     // particles
#define DD 128                     // dims
#define NPAIRS (NP * (NP - 1) / 2) // 130816
#define PPT 256                    // pairs per thread (ceil NPAIRS/512)
#define NBIN 1024
#define MAXLEV 4

// Hybrid bitonic sort of 512 floats (ascending): value in register r, one per
// thread; __shfl_xor for partner distance < 64, LDS exchange for s >= 64.
__device__ __forceinline__ float bitonic512(float r, int tid, float* lds)
{
    for (int k = 2; k <= NP; k <<= 1) {
        for (int s = k >> 1; s > 0; s >>= 1) {
            float other;
            if (s < 64) {
                other = __shfl_xor(r, s);
            } else {
                __syncthreads();
                lds[tid] = r;
                __syncthreads();
                other = lds[tid ^ s];
            }
            const bool lower = (tid & s) == 0;
            const bool up    = (tid & k) == 0;
            r = (lower == up) ? fminf(r, other) : fmaxf(r, other);
        }
    }
    return r;
}

__device__ __forceinline__ int binof(float x, float o, float s)
{
    int b = (int)((x - o) * s);
    return b < 0 ? 0 : (b > NBIN - 1 ? NBIN - 1 : b);
}

// ---------------------------------------------------------------------------
// Kernel 1: per-dimension exact median of pairwise squared differences via
// histogram selection (NO sort, NO bisection). One block / dim, 512 threads.
//   - median(sq diffs) = Dk^2 where Dk = rank-want1 |diff| (x->fl(x^2) and
//     negation are monotone/exact, so selecting on |fl(vj-vi)| is exact)
//   - each thread walks a flat 256-pair slice of the triangle (balanced)
//   - wave-private 1024-bin LDS histograms; bin map is monotone in x, so
//     each level partitions rank space exactly; refine only if bin > 512
//   - final: gather bin occupants (<=512), one bitonic sort, pick rank
// ---------------------------------------------------------------------------
__global__ void __launch_bounds__(512)
median_bw_kernel(const float* __restrict__ particles, float* __restrict__ inv_bw)
{
    const int d = blockIdx.x, tid = threadIdx.x, lane = tid & 63, wid = tid >> 6;

    __shared__ float v[NP];
    __shared__ int   hist[8][NBIN];
    __shared__ float red_s[2][8];
    __shared__ int   scan_s[8];
    __shared__ int   sel_s[3];     // {bin, prior_count, count_in_bin}
    __shared__ float cand[NP];
    __shared__ int   cand_n;

    const float x0 = particles[tid * DD + d];
    v[tid] = x0;

    // block min/max (also makes v[] visible)
    float mn = x0, mx = x0;
    #pragma unroll
    for (int off = 32; off > 0; off >>= 1) {
        mn = fminf(mn, __shfl_xor(mn, off));
        mx = fmaxf(mx, __shfl_xor(mx, off));
    }
    if (lane == 0) { red_s[0][wid] = mn; red_s[1][wid] = mx; }
    __syncthreads();
    float gmn = red_s[0][0], gmx = red_s[1][0];
    #pragma unroll
    for (int w = 1; w < 8; ++w) {
        gmn = fminf(gmn, red_s[0][w]);
        gmx = fmaxf(gmx, red_s[1][w]);
    }
    const float width = gmx - gmn;        // >= any |diff|
    if (!(width > 0.0f)) {                // degenerate: all values equal
        if (tid == 0) inv_bw[d] = 1.0f / 1e-9f;
        return;                           // uniform across block
    }

    // flat pair slice [f0, f0+cntp); pair (j,i), i<j, flat = j(j-1)/2 + i
    const int f0   = tid * PPT;
    const int cntp = min(PPT, max(0, NPAIRS - f0));
    int j0 = (int)((1.0f + __builtin_sqrtf(1.0f + 8.0f * (float)f0)) * 0.5f);
    if (j0 < 1) j0 = 1;
    while (j0 * (j0 - 1) / 2 > f0) --j0;
    while ((j0 + 1) * j0 / 2 <= f0) ++j0;
    const int i0 = f0 - j0 * (j0 - 1) / 2;

    // level chain (statically indexed; rule #20 — no runtime-indexed arrays)
    float o0 = 0.0f, s0 = (float)NBIN / width;
    float o1 = 0.0f, s1 = 0.0f, o2 = 0.0f, s2 = 0.0f, o3 = 0.0f, s3 = 0.0f;
    int   bs0 = 0, bs1 = 0, bs2 = 0, bs3 = 0;
    int   nlev = 0;
    int   want_rem = (NPAIRS - 1) / 2 + 1;   // 65408 (1-based rank)
    int   cnt_bin  = 0;

    while (true) {
        // zero wave-private histograms (8*1024 ints, 16/thread)
        #pragma unroll
        for (int z = 0; z < 16; ++z) ((int*)hist)[tid + 512 * z] = 0;
        __syncthreads();

        // histogram pass at level nlev, filtered by levels < nlev
        {
            int j = j0, i = i0;
            float vj = (cntp > 0) ? v[j] : 0.0f;
            for (int n = 0; n < cntp; ++n) {
                const float xv = fabsf(vj - v[i]);
                const int b0 = binof(xv, o0, s0);
                const int b1 = binof(xv, o1, s1);
                const int b2 = binof(xv, o2, s2);
                bool ok = true;
                ok &= (nlev < 1) | (b0 == bs0);
                ok &= (nlev < 2) | (b1 == bs1);
                ok &= (nlev < 3) | (b2 == bs2);
                const int bc = (nlev == 0) ? b0 : (nlev == 1) ? b1
                             : (nlev == 2) ? b2 : binof(xv, o3, s3);
                if (ok) atomicAdd(&hist[wid][bc], 1);
                if (++i == j) { ++j; i = 0; if (j < NP) vj = v[j]; }
            }
        }
        __syncthreads();

        // combine wave copies (2 bins/thread) + block scan -> rank bin
        int t0 = 0, t1 = 0;
        #pragma unroll
        for (int w = 0; w < 8; ++w) {
            t0 += hist[w][2 * tid];
            t1 += hist[w][2 * tid + 1];
        }
        const int p = t0 + t1;
        int inc = p;
        #pragma unroll
        for (int off = 1; off < 64; off <<= 1) {
            const int u = __shfl_up(inc, off);
            if (lane >= off) inc += u;
        }
        if (lane == 63) scan_s[wid] = inc;
        __syncthreads();
        int base = 0;
        #pragma unroll
        for (int w = 0; w < 8; ++w) base += (w < wid) ? scan_s[w] : 0;
        const int excl = base + inc - p;   // pairs in bins before 2*tid

        if (excl < want_rem && want_rem <= excl + t0) {
            sel_s[0] = 2 * tid;     sel_s[1] = excl;      sel_s[2] = t0;
        } else if (excl + t0 < want_rem && want_rem <= excl + t0 + t1) {
            sel_s[0] = 2 * tid + 1; sel_s[1] = excl + t0; sel_s[2] = t1;
        }
        __syncthreads();
        const int sbin = sel_s[0];
        want_rem -= sel_s[1];
        cnt_bin   = sel_s[2];
        __syncthreads();           // protect sel_s/scan_s before next level

        if (nlev == 0) bs0 = sbin; else if (nlev == 1) bs1 = sbin;
        else if (nlev == 2) bs2 = sbin; else bs3 = sbin;

        if (cnt_bin <= NP || nlev >= MAXLEV - 1) break;

        const float oc = (nlev == 0) ? o0 : (nlev == 1) ? o1 : o2;
        const float sc = (nlev == 0) ? s0 : (nlev == 1) ? s1 : s2;
        const float no = oc + (float)sbin / sc;
        const float ns = sc * (float)NBIN;
        if (nlev == 0)      { o1 = no; s1 = ns; }
        else if (nlev == 1) { o2 = no; s2 = ns; }
        else                { o3 = no; s3 = ns; }
        ++nlev;
    }

    // collect pass: all levels 0..nlev must match
    if (tid == 0) cand_n = 0;
    __syncthreads();
    {
        int j = j0, i = i0;
        float vj = (cntp > 0) ? v[j] : 0.0f;
        for (int n = 0; n < cntp; ++n) {
            const float xv = fabsf(vj - v[i]);
            bool ok = (binof(xv, o0, s0) == bs0);
            ok &= (nlev < 1) | (binof(xv, o1, s1) == bs1);
            ok &= (nlev < 2) | (binof(xv, o2, s2) == bs2);
            ok &= (nlev < 3) | (binof(xv, o3, s3) == bs3);
            if (ok) {
                const int idx = atomicAdd(&cand_n, 1);
                if (idx < NP) cand[idx] = xv;
            }
            if (++i == j) { ++j; i = 0; if (j < NP) vj = v[j]; }
        }
    }
    __syncthreads();
    const int T = min(cand_n, NP);
    float c = (tid < T) ? cand[tid] : INFINITY;
    c = bitonic512(c, tid, v);     // v no longer needed; reuse as scratch

    const int rr = min(want_rem, T);
    if (tid == rr - 1) {
        const float Dk     = c;
        const float median = Dk * Dk;
        const float h      = median / 6.240275844172107f;  // ln(513)
        const float bw     = fmaxf(h, 1e-9f);
        inv_bw[d] = 1.0f / bw;
    }
}

// ---------------------------------------------------------------------------
// Kernel 2: write log_kernel and grad_log_kernel, float4-vectorized,
// PLAIN stores (nontemporal stores regressed write BW ~2.4x in R4).
// Flat float4 index t over (i, j, d4):  d4 = t & 31, j = (t>>5)&511, i = t>>14
// ---------------------------------------------------------------------------
__global__ void __launch_bounds__(256)
stein_out_kernel(const float* __restrict__ particles,
                 const float* __restrict__ inv_bw,
                 float4* __restrict__ out_lk,
                 float4* __restrict__ out_g)
{
    const float4* __restrict__ p4  = (const float4*)particles;
    const float4* __restrict__ ib4 = (const float4*)inv_bw;
    const int total = NP * NP * (DD / 4);   // 8,388,608

    for (int t = blockIdx.x * blockDim.x + threadIdx.x; t < total;
         t += gridDim.x * blockDim.x) {
        const int d4 = t & (DD / 4 - 1);        // 0..31
        const int j  = (t >> 5) & (NP - 1);     // 0..511
        const int i  = t >> 14;                 // 0..511

        const float4 xj = p4[j * (DD / 4) + d4];
        const float4 xi = p4[i * (DD / 4) + d4];
        const float4 ib = ib4[d4];

        float4 lk, g;
        {
            const float dx = xj.x - xi.x;
            lk.x = -(dx * dx * ib.x);
            g.x  = -2.0f * dx * ib.x;
        }
        {
            const float dx = xj.y - xi.y;
            lk.y = -(dx * dx * ib.y);
            g.y  = -2.0f * dx * ib.y;
        }
        {
            const float dx = xj.z - xi.z;
            lk.z = -(dx * dx * ib.z);
            g.z  = -2.0f * dx * ib.z;
        }
        {
            const float dx = xj.w - xi.w;
            lk.w = -(dx * dx * ib.w);
            g.w  = -2.0f * dx * ib.w;
        }
        out_lk[t] = lk;
        out_g[t]  = g;
    }
}

extern "C" void kernel_launch(void* const* d_in, const int* in_sizes, int n_in,
                              void* d_out, int out_size, void* d_ws, size_t ws_size,
                              hipStream_t stream)
{
    const float* particles = (const float*)d_in[0];
    float* out    = (float*)d_out;
    float* inv_bw = (float*)d_ws;   // 128 floats of scratch

    median_bw_kernel<<<DD, 512, 0, stream>>>(particles, inv_bw);

    float4* out_lk = (float4*)out;
    float4* out_g  = (float4*)(out + (size_t)NP * NP * DD);
    stein_out_kernel<<<2048, 256, 0, stream>>>(particles, inv_bw, out_lk, out_g);
}

// Round 9
// 110.345 us; speedup vs baseline: 1.3520x; 1.3520x over previous
//
#include <hip/hip_runtime.h>
#include <hip/hip_bf16.h>

#define NP 512                     // particles
#define DD 128                     // dims
#define NPAIRS (NP * (NP - 1) / 2) // 130816

// Hybrid bitonic sort of 512 floats (ascending): value in register r, one per
// thread; __shfl_xor for partner distance < 64, LDS exchange for s >= 64.
__device__ __forceinline__ float bitonic512(float r, int tid, float* lds)
{
    for (int k = 2; k <= NP; k <<= 1) {
        for (int s = k >> 1; s > 0; s >>= 1) {
            float other;
            if (s < 64) {
                other = __shfl_xor(r, s);
            } else {
                __syncthreads();
                lds[tid] = r;
                __syncthreads();
                other = lds[tid ^ s];
            }
            const bool lower = (tid & s) == 0;
            const bool up    = (tid & k) == 0;
            r = (lower == up) ? fminf(r, other) : fmaxf(r, other);
        }
    }
    return r;
}

// ---------------------------------------------------------------------------
// Kernel 1: per-dimension exact median of upper-triangular pairwise squared
// differences. One block (512 threads) per dimension d.
//   1) bitonic sort -> v[] (LDS); thread owns j = tid, vj = v[j]
//   2) verified-pivot rounds: pivot0 = mean of offset-150 diffs (rank-65408
//      pair sits at sorted offset ~150; mean of that band ~ the answer);
//      then rank-interpolation pivots (bit-midpoint every 3rd round as
//      safeguard). Every pivot is VERIFIED by an exact count, so correctness
//      never depends on the guesses. count via per-j warm windows [A,B]
//      (Σ(B-A) == C_hi - C_lo == T) searched with a 4-ary select-only probe
//      (3 independent LDS loads per step, 7 fixed steps). 1 barrier/round.
//   3) endgame when T <= 512: gather candidates (prefix-sum offsets), one
//      bitonic sort, answer = rank (want1 - C_lo).
//   median(squared diffs) = Dk*Dk (x -> fl(x^2) monotone on non-neg floats)
// ---------------------------------------------------------------------------
__global__ void __launch_bounds__(512)
median_bw_kernel(const float* __restrict__ particles, float* __restrict__ inv_bw)
{
    const int d = blockIdx.x, tid = threadIdx.x, lane = tid & 63, wid = tid >> 6;

    __shared__ float v[NP];
    __shared__ float cand[NP];
    __shared__ int   cnt_s[2][8];
    __shared__ float sum_s[8];
    __shared__ int   scan_s[8];

    float r = particles[tid * DD + d];
    r = bitonic512(r, tid, v);
    __syncthreads();          // WAR vs last cross-stage reads inside sort
    v[tid] = r;
    __syncthreads();          // sorted array visible to all

    const float vj = r;       // sorted value owned by this thread (j = tid)
    const int want1 = (NPAIRS - 1) / 2 + 1;   // 65408 (1-based rank)

    // ---- pivot 0: mean of the 362 offset-150 diffs ----
    float s = (tid >= 150) ? (vj - v[tid - 150]) : 0.0f;
    #pragma unroll
    for (int off = 32; off > 0; off >>= 1) s += __shfl_xor(s, off);
    if (lane == 0) sum_s[wid] = s;
    __syncthreads();
    float msum = 0.0f;
    #pragma unroll
    for (int w = 0; w < 8; ++w) msum += sum_s[w];
    const float meanp = fmaxf(msum / 362.0f, 0.0f);   // uniform across block

    const float maxd = v[NP - 1] - v[0];
    unsigned lo = 0u;
    unsigned hi = __float_as_uint(maxd) + 1u;   // answer bits in [lo, hi]
    int C_lo = 0;                   // count at pred(lo)   (< want1)
    int C_hi = NPAIRS;              // count at hi         (>= want1)
    int A = 0, B = tid;             // warm window: A <= L_j(x) <= B, x in [lo,hi]
    int buf = 0, round = 0;

    while (lo < hi) {
        if (C_hi - C_lo <= NP) break;    // endgame

        unsigned mid;
        if (round == 0) {
            mid = __float_as_uint(meanp);
        } else if (round % 3 == 0) {     // safeguard: bit midpoint
            mid = lo + ((hi - lo) >> 1);
        } else {                         // rank interpolation, value space
            const float flo  = __uint_as_float(lo);
            const float fhi  = __uint_as_float(hi);
            const float frac = (float)(want1 - C_lo) / (float)(C_hi - C_lo);
            mid = __float_as_uint(flo + (fhi - flo) * frac);
        }
        if (mid < lo)      mid = lo;
        if (mid > hi - 1u) mid = hi - 1u;
        const float x = __uint_as_float(mid);

        // 4-ary select-only lower_bound in warm window [a,b]
        int a = A, b = B;
        #pragma unroll
        for (int step = 0; step < 7; ++step) {
            const int w  = b - a;
            const int q  = w >> 2;
            const int m1 = a + q, m2 = a + 2 * q, m3 = a + 3 * q;
            const float p1 = v[m1], p2 = v[m2], p3 = v[m3];  // independent loads
            const bool t1 = (vj - p1 <= x);
            const bool t2 = (vj - p2 <= x);
            const bool t3 = (vj - p3 <= x);   // t1 <= t2 <= t3 (monotone)
            const int na = t1 ? a  : (t2 ? m1 + 1 : (t3 ? m2 + 1 : m3 + 1));
            const int nb = t1 ? m1 : (t2 ? m2     : (t3 ? m3     : b     ));
            a = (w > 0) ? na : a;
            b = (w > 0) ? nb : b;
        }
        while (a < b) {                  // safety net (normally 0 iters)
            const int m = (a + b) >> 1;
            if (vj - v[m] <= x) b = m; else a = m + 1;
        }
        int cnt = tid - a;               // #{i<j : fl(vj-vi) <= x}

        #pragma unroll
        for (int off = 32; off > 0; off >>= 1) cnt += __shfl_xor(cnt, off);
        if (lane == 0) cnt_s[buf][wid] = cnt;
        __syncthreads();                 // the ONLY barrier in the round
        int tot = 0;
        #pragma unroll
        for (int w = 0; w < 8; ++w) tot += cnt_s[buf][w];

        if (tot >= want1) { hi = mid;      C_hi = tot; A = a; }
        else              { lo = mid + 1u; C_lo = tot; B = a; }
        buf ^= 1;
        ++round;
    }

    if (lo >= hi) {
        // bracket collapsed to a single bit pattern: that's the answer
        if (tid == 0) {
            const float Dk = __uint_as_float(lo);
            const float h  = (Dk * Dk) / 6.240275844172107f;  // ln(513)
            inv_bw[d] = 1.0f / fmaxf(h, 1e-9f);
        }
    } else {
        // ---- endgame: T (<=512) candidates, rank rr within them ----
        const int T  = C_hi - C_lo;
        const int rr = min(want1 - C_lo, T);  // 1-based, 1 <= rr <= T
        const int n  = B - A;                 // this thread's candidates
        int inc = n;                          // wave inclusive scan
        #pragma unroll
        for (int off = 1; off < 64; off <<= 1) {
            const int t = __shfl_up(inc, off);
            if (lane >= off) inc += t;
        }
        if (lane == 63) scan_s[wid] = inc;
        __syncthreads();
        int woff = 0;
        #pragma unroll
        for (int w = 0; w < 8; ++w) woff += (w < wid) ? scan_s[w] : 0;
        int off0 = woff + inc - n;            // exclusive global offset
        for (int i = A; i < B; ++i) cand[off0++] = vj - v[i];
        __syncthreads();

        float c = (tid < T) ? cand[tid] : INFINITY;
        c = bitonic512(c, tid, v);            // v reusable as scratch now

        if (tid == rr - 1) {
            const float Dk = c;
            const float h  = (Dk * Dk) / 6.240275844172107f;  // ln(513)
            inv_bw[d] = 1.0f / fmaxf(h, 1e-9f);
        }
    }
}

// ---------------------------------------------------------------------------
// Kernel 2: write log_kernel and grad_log_kernel, float4-vectorized,
// PLAIN stores (nontemporal stores regressed write BW ~2.4x in R4).
// Flat float4 index t over (i, j, d4):  d4 = t & 31, j = (t>>5)&511, i = t>>14
// ---------------------------------------------------------------------------
__global__ void __launch_bounds__(256)
stein_out_kernel(const float* __restrict__ particles,
                 const float* __restrict__ inv_bw,
                 float4* __restrict__ out_lk,
                 float4* __restrict__ out_g)
{
    const float4* __restrict__ p4  = (const float4*)particles;
    const float4* __restrict__ ib4 = (const float4*)inv_bw;
    const int total = NP * NP * (DD / 4);   // 8,388,608

    for (int t = blockIdx.x * blockDim.x + threadIdx.x; t < total;
         t += gridDim.x * blockDim.x) {
        const int d4 = t & (DD / 4 - 1);        // 0..31
        const int j  = (t >> 5) & (NP - 1);     // 0..511
        const int i  = t >> 14;                 // 0..511

        const float4 xj = p4[j * (DD / 4) + d4];
        const float4 xi = p4[i * (DD / 4) + d4];
        const float4 ib = ib4[d4];

        float4 lk, g;
        {
            const float dx = xj.x - xi.x;
            lk.x = -(dx * dx * ib.x);
            g.x  = -2.0f * dx * ib.x;
        }
        {
            const float dx = xj.y - xi.y;
            lk.y = -(dx * dx * ib.y);
            g.y  = -2.0f * dx * ib.y;
        }
        {
            const float dx = xj.z - xi.z;
            lk.z = -(dx * dx * ib.z);
            g.z  = -2.0f * dx * ib.z;
        }
        {
            const float dx = xj.w - xi.w;
            lk.w = -(dx * dx * ib.w);
            g.w  = -2.0f * dx * ib.w;
        }
        out_lk[t] = lk;
        out_g[t]  = g;
    }
}

extern "C" void kernel_launch(void* const* d_in, const int* in_sizes, int n_in,
                              void* d_out, int out_size, void* d_ws, size_t ws_size,
                              hipStream_t stream)
{
    const float* particles = (const float*)d_in[0];
    float* out    = (float*)d_out;
    float* inv_bw = (float*)d_ws;   // 128 floats of scratch

    median_bw_kernel<<<DD, 512, 0, stream>>>(particles, inv_bw);

    float4* out_lk = (float4*)out;
    float4* out_g  = (float4*)(out + (size_t)NP * NP * DD);
    stein_out_kernel<<<2048, 256, 0, stream>>>(particles, inv_bw, out_lk, out_g);
}

// Round 10
// 83.861 us; speedup vs baseline: 1.7789x; 1.3158x over previous
//
#include <hip/hip_runtime.h>
#include <hip/hip_bf16.h>

#define NP 512                     // particles
#define DD 128                     // dims
#define NPAIRS (NP * (NP - 1) / 2) // 130816
#define TBIN 2048                  // CDF hint table bins

// Hybrid bitonic sort of 512 floats (ascending): value in register r, one per
// thread; __shfl_xor for partner distance < 64, LDS exchange for s >= 64.
__device__ __forceinline__ float bitonic512(float r, int tid, float* lds)
{
    for (int k = 2; k <= NP; k <<= 1) {
        for (int s = k >> 1; s > 0; s >>= 1) {
            float other;
            if (s < 64) {
                other = __shfl_xor(r, s);
            } else {
                __syncthreads();
                lds[tid] = r;
                __syncthreads();
                other = lds[tid ^ s];
            }
            const bool lower = (tid & s) == 0;
            const bool up    = (tid & k) == 0;
            r = (lower == up) ? fminf(r, other) : fmaxf(r, other);
        }
    }
    return r;
}

// lower_bound of pred(i) = (fl(vj - v[i]) <= x) over [a,b] (pred monotone
// false..false,true..true; returns first true, or b). t0 is a hint; result
// is EXACT regardless of hint (gallop + binary with the true predicate).
__device__ __forceinline__ int lbound_hint(const float* v, float vj, float x,
                                           int a, int b, int t0)
{
    if (a >= b) return a;
    t0 = t0 < a ? a : (t0 > b - 1 ? b - 1 : t0);
    if (vj - v[t0] <= x) {
        // L <= t0: gallop left
        int hi2 = t0, step = 1;
        while (hi2 - step >= a && (vj - v[hi2 - step] <= x)) {
            hi2 -= step; step <<= 1;
        }
        int lo2 = (hi2 - step < a) ? a : hi2 - step;
        while (lo2 < hi2) {
            const int m = (lo2 + hi2) >> 1;
            if (vj - v[m] <= x) hi2 = m; else lo2 = m + 1;
        }
        return lo2;
    } else {
        // L > t0: gallop right
        int lo2 = t0 + 1, step = 1;
        while (lo2 + step - 1 < b && !(vj - v[lo2 + step - 1] <= x)) {
            lo2 += step; step <<= 1;
        }
        int hi2 = (lo2 + step - 1 > b) ? b : lo2 + step - 1;
        while (lo2 < hi2) {
            const int m = (lo2 + hi2) >> 1;
            if (vj - v[m] <= x) hi2 = m; else lo2 = m + 1;
        }
        return lo2;
    }
}

// ---------------------------------------------------------------------------
// Kernel 1: per-dimension exact median of upper-triangular pairwise squared
// differences. One block (512 threads) per dimension d.
//   1) bitonic sort -> v[] (LDS); thread owns j = tid, vj = v[j]
//   2) one-time 2048-bin CDF hint table over v (scatter build): lookup gives
//      a start index for lower_bound; exactness via true-predicate
//      gallop+binary clamped to warm window [A,B] (table = acceleration only)
//   3) verified-pivot rounds (R7 policy): round0 = mean of offset-150 band,
//      then odd rounds rank-interpolation, even rounds bit-midpoint (strict
//      alternation -> no false-position stagnation). count(x)=Σ(j - L_j(x)),
//      butterfly + 1 barrier per round.
//   4) endgame when T = C_hi-C_lo <= 512: gather candidates (prefix-sum
//      offsets), one bitonic sort, answer = rank (want1 - C_lo).
//   median(squared diffs) = Dk*Dk (x -> fl(x^2) monotone on non-neg floats)
// ---------------------------------------------------------------------------
__global__ void __launch_bounds__(512)
median_bw_kernel(const float* __restrict__ particles, float* __restrict__ inv_bw)
{
    const int d = blockIdx.x, tid = threadIdx.x, lane = tid & 63, wid = tid >> 6;

    __shared__ float v[NP];
    __shared__ float cand[NP];
    __shared__ int   cnt_s[2][8];
    __shared__ float sum_s[8];
    __shared__ int   scan_s[8];
    __shared__ unsigned short tab[TBIN];

    float r = particles[tid * DD + d];
    r = bitonic512(r, tid, v);
    __syncthreads();          // WAR vs last cross-stage reads inside sort
    v[tid] = r;
    __syncthreads();          // sorted array visible to all

    const float vj = r;       // sorted value owned by this thread (j = tid)
    const int want1 = (NPAIRS - 1) / 2 + 1;   // 65408 (1-based rank)

    const float gmn = v[0], gmx = v[NP - 1];
    const float width = gmx - gmn;
    if (!(width > 0.0f)) {    // degenerate: all equal -> median 0 -> bw 1e-9
        if (tid == 0) inv_bw[d] = 1.0f / 1e-9f;
        return;               // uniform across block
    }
    const float tscale = (float)TBIN / width;

    // ---- build CDF hint table: tab[b] = first idx whose bin >= b ----
    {
        int bc = (int)((v[tid] - gmn) * tscale);
        bc = bc < 0 ? 0 : (bc > TBIN - 1 ? TBIN - 1 : bc);
        int bp = -1;
        if (tid > 0) {
            bp = (int)((v[tid - 1] - gmn) * tscale);
            bp = bp < 0 ? 0 : (bp > TBIN - 1 ? TBIN - 1 : bp);
        }
        for (int b = bp + 1; b <= bc; ++b) tab[b] = (unsigned short)tid;
    }
    // (published by the barrier in the mean reduce below)

    // ---- pivot 0: mean of the 362 offset-150 diffs ----
    float s = (tid >= 150) ? (vj - v[tid - 150]) : 0.0f;
    #pragma unroll
    for (int off = 32; off > 0; off >>= 1) s += __shfl_xor(s, off);
    if (lane == 0) sum_s[wid] = s;
    __syncthreads();          // publishes tab[] AND sum_s[]
    float msum = 0.0f;
    #pragma unroll
    for (int w = 0; w < 8; ++w) msum += sum_s[w];
    const float meanp = fmaxf(msum / 362.0f, 0.0f);   // uniform across block

    unsigned lo = 0u;
    unsigned hi = __float_as_uint(width) + 1u;  // answer bits in [lo, hi]
    int C_lo = 0;                   // count at pred(lo)   (< want1)
    int C_hi = NPAIRS;              // count at hi         (>= want1)
    int A = 0, B = tid;             // warm window: A <= L_j(x) <= B, x in [lo,hi]
    int buf = 0, round = 0;

    while (lo < hi) {
        if (C_hi - C_lo <= NP) break;    // endgame

        unsigned mid;
        if (round == 0) {
            mid = __float_as_uint(meanp);
        } else if (round & 1) {          // rank interpolation, value space
            const float flo  = __uint_as_float(lo);
            const float fhi  = __uint_as_float(hi);
            const float frac = (float)(want1 - C_lo) / (float)(C_hi - C_lo);
            mid = __float_as_uint(flo + (fhi - flo) * frac);
        } else {                         // safeguard: bit midpoint
            mid = lo + ((hi - lo) >> 1);
        }
        if (mid < lo)      mid = lo;
        if (mid > hi - 1u) mid = hi - 1u;
        const float x = __uint_as_float(mid);

        // table-hinted exact lower_bound in warm window [A,B]
        const float key = vj - x;
        int tb = (int)((key - gmn) * tscale);
        tb = tb < 0 ? 0 : (tb > TBIN - 1 ? TBIN - 1 : tb);
        const int a = lbound_hint(v, vj, x, A, B, (int)tab[tb]);
        int cnt = tid - a;               // #{i<j : fl(vj-vi) <= x}

        #pragma unroll
        for (int off = 32; off > 0; off >>= 1) cnt += __shfl_xor(cnt, off);
        if (lane == 0) cnt_s[buf][wid] = cnt;
        __syncthreads();                 // the ONLY barrier in the round
        int tot = 0;
        #pragma unroll
        for (int w = 0; w < 8; ++w) tot += cnt_s[buf][w];

        if (tot >= want1) { hi = mid;      C_hi = tot; A = a; }
        else              { lo = mid + 1u; C_lo = tot; B = a; }
        buf ^= 1;
        ++round;
    }

    if (lo >= hi) {
        // bracket collapsed to a single bit pattern: that's the answer
        if (tid == 0) {
            const float Dk = __uint_as_float(lo);
            const float h  = (Dk * Dk) / 6.240275844172107f;  // ln(513)
            inv_bw[d] = 1.0f / fmaxf(h, 1e-9f);
        }
    } else {
        // ---- endgame: T (<=512) candidates, rank rr within them ----
        const int T  = C_hi - C_lo;
        const int rr = min(want1 - C_lo, T);  // 1-based, 1 <= rr <= T
        const int n  = B - A;                 // this thread's candidates
        int inc = n;                          // wave inclusive scan
        #pragma unroll
        for (int off = 1; off < 64; off <<= 1) {
            const int t = __shfl_up(inc, off);
            if (lane >= off) inc += t;
        }
        if (lane == 63) scan_s[wid] = inc;
        __syncthreads();
        int woff = 0;
        #pragma unroll
        for (int w = 0; w < 8; ++w) woff += (w < wid) ? scan_s[w] : 0;
        int off0 = woff + inc - n;            // exclusive global offset
        for (int i = A; i < B; ++i) cand[off0++] = vj - v[i];
        __syncthreads();

        float c = (tid < T) ? cand[tid] : INFINITY;
        c = bitonic512(c, tid, v);            // v reusable as scratch now

        if (tid == rr - 1) {
            const float Dk = c;
            const float h  = (Dk * Dk) / 6.240275844172107f;  // ln(513)
            inv_bw[d] = 1.0f / fmaxf(h, 1e-9f);
        }
    }
}

// ---------------------------------------------------------------------------
// Kernel 2: write log_kernel and grad_log_kernel, float4-vectorized,
// PLAIN stores (nontemporal stores regressed write BW ~2.4x in R4).
// Flat float4 index t over (i, j, d4):  d4 = t & 31, j = (t>>5)&511, i = t>>14
// ---------------------------------------------------------------------------
__global__ void __launch_bounds__(256)
stein_out_kernel(const float* __restrict__ particles,
                 const float* __restrict__ inv_bw,
                 float4* __restrict__ out_lk,
                 float4* __restrict__ out_g)
{
    const float4* __restrict__ p4  = (const float4*)particles;
    const float4* __restrict__ ib4 = (const float4*)inv_bw;
    const int total = NP * NP * (DD / 4);   // 8,388,608

    for (int t = blockIdx.x * blockDim.x + threadIdx.x; t < total;
         t += gridDim.x * blockDim.x) {
        const int d4 = t & (DD / 4 - 1);        // 0..31
        const int j  = (t >> 5) & (NP - 1);     // 0..511
        const int i  = t >> 14;                 // 0..511

        const float4 xj = p4[j * (DD / 4) + d4];
        const float4 xi = p4[i * (DD / 4) + d4];
        const float4 ib = ib4[d4];

        float4 lk, g;
        {
            const float dx = xj.x - xi.x;
            lk.x = -(dx * dx * ib.x);
            g.x  = -2.0f * dx * ib.x;
        }
        {
            const float dx = xj.y - xi.y;
            lk.y = -(dx * dx * ib.y);
            g.y  = -2.0f * dx * ib.y;
        }
        {
            const float dx = xj.z - xi.z;
            lk.z = -(dx * dx * ib.z);
            g.z  = -2.0f * dx * ib.z;
        }
        {
            const float dx = xj.w - xi.w;
            lk.w = -(dx * dx * ib.w);
            g.w  = -2.0f * dx * ib.w;
        }
        out_lk[t] = lk;
        out_g[t]  = g;
    }
}

extern "C" void kernel_launch(void* const* d_in, const int* in_sizes, int n_in,
                              void* d_out, int out_size, void* d_ws, size_t ws_size,
                              hipStream_t stream)
{
    const float* particles = (const float*)d_in[0];
    float* out    = (float*)d_out;
    float* inv_bw = (float*)d_ws;   // 128 floats of scratch

    median_bw_kernel<<<DD, 512, 0, stream>>>(particles, inv_bw);

    float4* out_lk = (float4*)out;
    float4* out_g  = (float4*)(out + (size_t)NP * NP * DD);
    stein_out_kernel<<<2048, 256, 0, stream>>>(particles, inv_bw, out_lk, out_g);
}

// Round 11
// 68.832 us; speedup vs baseline: 2.1673x; 1.2183x over previous
//
#include <hip/hip_runtime.h>
#include <hip/hip_bf16.h>

#define NP 512                     // particles
#define DD 128                     // dims
#define NPAIRS (NP * (NP - 1) / 2) // 130816

// Hybrid bitonic sort of 512 floats (ascending): value in register r, one per
// thread; __shfl_xor for partner distance < 64, LDS exchange for s >= 64.
__device__ __forceinline__ float bitonic512(float r, int tid, float* lds)
{
    for (int k = 2; k <= NP; k <<= 1) {
        for (int s = k >> 1; s > 0; s >>= 1) {
            float other;
            if (s < 64) {
                other = __shfl_xor(r, s);
            } else {
                __syncthreads();
                lds[tid] = r;
                __syncthreads();
                other = lds[tid ^ s];
            }
            const bool lower = (tid & s) == 0;
            const bool up    = (tid & k) == 0;
            r = (lower == up) ? fminf(r, other) : fmaxf(r, other);
        }
    }
    return r;
}

// ---------------------------------------------------------------------------
// Kernel 1: per-dimension exact median of upper-triangular pairwise squared
// differences. One block (512 threads) per dimension d.
//   1) bitonic sort -> v[] (LDS); thread owns j = tid, vj = v[j]
//   2) verified-pivot rounds, ILLINOIS false-position policy:
//      round0 = mean of offset-150 diffs; then secant pivot in value space
//      on count-residuals (g_lo<0<g_hi), halving the opposite residual when
//      the same side updates twice (kills regula-falsi creep, which made R7
//      burn ~25 rounds); pivot clamped >= span/8 from both bracket ends in
//      bit space; every 4th round = bit midpoint (hard safeguard).
//      Every pivot is VERIFIED by an exact count — correctness never depends
//      on the policy. count via per-j warm windows [A,B] and the plain
//      select-only binary search (R7's proven primitive). 1 barrier/round.
//   3) endgame when T = C_hi-C_lo <= 512: gather candidates (prefix-sum
//      offsets), one bitonic sort, answer = rank (want1 - C_lo).
//   median(squared diffs) = Dk*Dk (x -> fl(x^2) monotone on non-neg floats)
// ---------------------------------------------------------------------------
__global__ void __launch_bounds__(512)
median_bw_kernel(const float* __restrict__ particles, float* __restrict__ inv_bw)
{
    const int d = blockIdx.x, tid = threadIdx.x, lane = tid & 63, wid = tid >> 6;

    __shared__ float v[NP];
    __shared__ float cand[NP];
    __shared__ int   cnt_s[2][8];
    __shared__ float sum_s[8];
    __shared__ int   scan_s[8];

    float r = particles[tid * DD + d];
    r = bitonic512(r, tid, v);
    __syncthreads();          // WAR vs last cross-stage reads inside sort
    v[tid] = r;
    __syncthreads();          // sorted array visible to all

    const float vj = r;       // sorted value owned by this thread (j = tid)
    const int want1 = (NPAIRS - 1) / 2 + 1;   // 65408 (1-based rank)

    // ---- pivot 0: mean of the 362 offset-150 diffs ----
    float s = (tid >= 150) ? (vj - v[tid - 150]) : 0.0f;
    #pragma unroll
    for (int off = 32; off > 0; off >>= 1) s += __shfl_xor(s, off);
    if (lane == 0) sum_s[wid] = s;
    __syncthreads();
    float msum = 0.0f;
    #pragma unroll
    for (int w = 0; w < 8; ++w) msum += sum_s[w];
    const float meanp = fmaxf(msum / 362.0f, 0.0f);   // uniform across block

    const float maxd = v[NP - 1] - v[0];
    unsigned lo = 0u;
    unsigned hi = __float_as_uint(maxd) + 1u;   // answer bits in [lo, hi]
    int C_lo = 0;                   // count at pred(lo)   (< want1)
    int C_hi = NPAIRS;              // count at hi         (>= want1)
    int A = 0, B = tid;             // warm window: A <= L_j(x) <= B, x in [lo,hi]
    int buf = 0, round = 0;

    // Illinois state: residuals g_lo < 0 < g_hi, last updated side
    float g_lo = 0.5f - (float)want1;
    float g_hi = (float)(NPAIRS - want1) + 0.5f;
    int   last = 0;

    while (lo < hi) {
        if (C_hi - C_lo <= NP) break;    // endgame

        const unsigned span = hi - lo;
        unsigned mid;
        if (round == 0) {
            mid = __float_as_uint(meanp);
        } else if ((round & 3) == 3) {   // hard safeguard: bit midpoint
            mid = lo + (span >> 1);
        } else {                         // Illinois secant, value space
            const float flo = __uint_as_float(lo);
            const float fhi = __uint_as_float(hi);
            const float xn  = (flo * g_hi - fhi * g_lo) / (g_hi - g_lo);
            mid = __float_as_uint(xn);
        }
        const unsigned dlt = span >> 3;  // force interior progress
        if (mid < lo + dlt)            mid = lo + dlt;
        if (mid > hi - 1u - dlt)       mid = (hi - 1u) - dlt;
        if (mid < lo)                  mid = lo;        // span<8 fallback
        if (mid > hi - 1u)             mid = hi - 1u;
        const float x = __uint_as_float(mid);

        // warm-started select-only lower_bound in [A,B] (R7 primitive)
        int a = A, b = B;
        while (a < b) {
            const int   m  = (a + b) >> 1;
            const float pv = v[m];
            const bool  t  = (vj - pv <= x);
            b = t ? m : b;
            a = t ? a : m + 1;
        }
        int cnt = tid - a;               // #{i<j : fl(vj-vi) <= x}

        #pragma unroll
        for (int off = 32; off > 0; off >>= 1) cnt += __shfl_xor(cnt, off);
        if (lane == 0) cnt_s[buf][wid] = cnt;
        __syncthreads();                 // the ONLY barrier in the round
        int tot = 0;
        #pragma unroll
        for (int w = 0; w < 8; ++w) tot += cnt_s[buf][w];

        if (tot >= want1) {
            hi = mid; C_hi = tot; A = a;
            g_hi = (float)(tot - want1) + 0.5f;
            if (last == 1) g_lo *= 0.5f;     // same side twice: Illinois
            last = 1;
        } else {
            lo = mid + 1u; C_lo = tot; B = a;
            g_lo = (float)(tot - want1) + 0.5f;
            if (last == -1) g_hi *= 0.5f;
            last = -1;
        }
        buf ^= 1;
        ++round;
    }

    if (lo >= hi) {
        // bracket collapsed to a single bit pattern: that's the answer
        if (tid == 0) {
            const float Dk = __uint_as_float(lo);
            const float h  = (Dk * Dk) / 6.240275844172107f;  // ln(513)
            inv_bw[d] = 1.0f / fmaxf(h, 1e-9f);
        }
    } else {
        // ---- endgame: T (<=512) candidates, rank rr within them ----
        const int T  = C_hi - C_lo;
        const int rr = min(want1 - C_lo, T);  // 1-based, 1 <= rr <= T
        const int n  = B - A;                 // this thread's candidates
        int inc = n;                          // wave inclusive scan
        #pragma unroll
        for (int off = 1; off < 64; off <<= 1) {
            const int t = __shfl_up(inc, off);
            if (lane >= off) inc += t;
        }
        if (lane == 63) scan_s[wid] = inc;
        __syncthreads();
        int woff = 0;
        #pragma unroll
        for (int w = 0; w < 8; ++w) woff += (w < wid) ? scan_s[w] : 0;
        int off0 = woff + inc - n;            // exclusive global offset
        for (int i = A; i < B; ++i) cand[off0++] = vj - v[i];
        __syncthreads();

        float c = (tid < T) ? cand[tid] : INFINITY;
        c = bitonic512(c, tid, v);            // v reusable as scratch now

        if (tid == rr - 1) {
            const float Dk = c;
            const float h  = (Dk * Dk) / 6.240275844172107f;  // ln(513)
            inv_bw[d] = 1.0f / fmaxf(h, 1e-9f);
        }
    }
}

// ---------------------------------------------------------------------------
// Kernel 2: write log_kernel and grad_log_kernel, float4-vectorized,
// PLAIN stores (nontemporal stores regressed write BW ~2.4x in R4).
// Flat float4 index t over (i, j, d4):  d4 = t & 31, j = (t>>5)&511, i = t>>14
// ---------------------------------------------------------------------------
__global__ void __launch_bounds__(256)
stein_out_kernel(const float* __restrict__ particles,
                 const float* __restrict__ inv_bw,
                 float4* __restrict__ out_lk,
                 float4* __restrict__ out_g)
{
    const float4* __restrict__ p4  = (const float4*)particles;
    const float4* __restrict__ ib4 = (const float4*)inv_bw;
    const int total = NP * NP * (DD / 4);   // 8,388,608

    for (int t = blockIdx.x * blockDim.x + threadIdx.x; t < total;
         t += gridDim.x * blockDim.x) {
        const int d4 = t & (DD / 4 - 1);        // 0..31
        const int j  = (t >> 5) & (NP - 1);     // 0..511
        const int i  = t >> 14;                 // 0..511

        const float4 xj = p4[j * (DD / 4) + d4];
        const float4 xi = p4[i * (DD / 4) + d4];
        const float4 ib = ib4[d4];

        float4 lk, g;
        {
            const float dx = xj.x - xi.x;
            lk.x = -(dx * dx * ib.x);
            g.x  = -2.0f * dx * ib.x;
        }
        {
            const float dx = xj.y - xi.y;
            lk.y = -(dx * dx * ib.y);
            g.y  = -2.0f * dx * ib.y;
        }
        {
            const float dx = xj.z - xi.z;
            lk.z = -(dx * dx * ib.z);
            g.z  = -2.0f * dx * ib.z;
        }
        {
            const float dx = xj.w - xi.w;
            lk.w = -(dx * dx * ib.w);
            g.w  = -2.0f * dx * ib.w;
        }
        out_lk[t] = lk;
        out_g[t]  = g;
    }
}

extern "C" void kernel_launch(void* const* d_in, const int* in_sizes, int n_in,
                              void* d_out, int out_size, void* d_ws, size_t ws_size,
                              hipStream_t stream)
{
    const float* particles = (const float*)d_in[0];
    float* out    = (float*)d_out;
    float* inv_bw = (float*)d_ws;   // 128 floats of scratch

    median_bw_kernel<<<DD, 512, 0, stream>>>(particles, inv_bw);

    float4* out_lk = (float4*)out;
    float4* out_g  = (float4*)(out + (size_t)NP * NP * DD);
    stein_out_kernel<<<2048, 256, 0, stream>>>(particles, inv_bw, out_lk, out_g);
}